// Round 1
// baseline (1113.190 us; speedup 1.0000x reference)
//
#include <hip/hip_runtime.h>

#define EE     1600000
#define NN     100000
#define NDIM   64
#define EDIM   32
#define NLAYER 3
#define INDIM  160      // EDIM + 2*NDIM
#define TPB    256
#define EPT    2
#define EPB    (TPB*EPT)   // 512 edges per block

static_assert(EE % EPB == 0, "grid must divide evenly");

// =====================================================================
// Kernel A: per-node projection precompute.
//   P[l][n][0:32]  = sum_{d<64} nf[n][d] * g_l[d]    * W1_l[d][k]     (i-part)
//   P[l][n][32:64] = sum_{d<64} nf[n][d] * g_l[64+d] * W1_l[64+d][k]  (j-part)
//   nstat[n] = (sum_d nf[n][d], sum_d nf[n][d]^2)   (layer-invariant LN partials)
//   cvec[0:96]   = C2[l][k]  = sum_{d<160} g_l[d]*W1_l[d][k]
//   cvec[96:192] = C1b[l][k] = b1[l][k] + sum_{d<160} lnb_l[d]*W1_l[d][k]
// 1.23 GMAC total — noise next to the edge kernel.
// =====================================================================
__global__ __launch_bounds__(TPB) void node_precompute(
  const float* __restrict__ nf,  const float* __restrict__ lng,
  const float* __restrict__ lnb, const float* __restrict__ w1,
  const float* __restrict__ b1,
  float* __restrict__ P, float* __restrict__ nstat, float* __restrict__ cvec)
{
  __shared__ float sW[NLAYER*128*EDIM];   // 48 KB: W1 rows 0..127, all layers
  __shared__ float sG[NLAYER*128];
  const int tid = threadIdx.x;

  // stage W1 rows 0..127 (3*128*32 = 12288 floats = 3072 float4, 12/thread)
  #pragma unroll
  for (int it = 0; it < 12; ++it){
    const int c = tid + it*TPB;
    const int l = c >> 10, rem = c & 1023;
    const int d = rem >> 3, ks = (rem & 7) * 4;
    float4 v = *(const float4*)(w1 + (size_t)l*INDIM*EDIM + d*EDIM + ks);
    float* dst = &sW[l*128*EDIM + d*EDIM + ks];
    dst[0]=v.x; dst[1]=v.y; dst[2]=v.z; dst[3]=v.w;
  }
  if (tid < 96){   // g rows 0..127, 3 layers = 384 floats = 96 float4
    const int l = tid >> 5, ks = (tid & 31) * 4;
    float4 v = *(const float4*)(lng + l*INDIM + ks);
    float* dst = &sG[l*128 + ks];
    dst[0]=v.x; dst[1]=v.y; dst[2]=v.z; dst[3]=v.w;
  }
  __syncthreads();

  // block 0 additionally produces the folded LN constant vectors
  if (blockIdx.x == 0 && tid < 96){
    const int l = tid >> 5, k = tid & 31;
    const float* wl = w1 + (size_t)l*INDIM*EDIM;
    float c2 = 0.f, c1 = b1[l*EDIM + k];
    for (int d = 0; d < INDIM; ++d){
      const float w = wl[d*EDIM + k];
      c2 = fmaf(lng[l*INDIM + d], w, c2);
      c1 = fmaf(lnb[l*INDIM + d], w, c1);
    }
    cvec[l*EDIM + k]      = c2;
    cvec[96 + l*EDIM + k] = c1;
  }

  const int n = blockIdx.x*TPB + tid;
  if (n >= NN) return;
  const float4* px = (const float4*)(nf + (size_t)n * NDIM);

  { // LN partial sums over the node's 64 features
    float s = 0.f, q = 0.f;
    #pragma unroll 1
    for (int c = 0; c < 16; ++c){
      float4 v = px[c];
      s += v.x + v.y + v.z + v.w;
      q = fmaf(v.x,v.x,q); q = fmaf(v.y,v.y,q);
      q = fmaf(v.z,v.z,q); q = fmaf(v.w,v.w,q);
    }
    nstat[2*n] = s; nstat[2*n+1] = q;
  }

  #pragma unroll 1
  for (int lp = 0; lp < NLAYER*2; ++lp){
    const int l = lp >> 1, part = lp & 1;
    float acc[EDIM];
    #pragma unroll
    for (int k = 0; k < EDIM; ++k) acc[k] = 0.f;
    const float* wbl = &sW[(l*128 + part*64) * EDIM];
    const float* gbl = &sG[l*128 + part*64];
    #pragma unroll 1
    for (int c = 0; c < 16; ++c){     // nf re-read from L1 — cheap, keeps VGPRs low
      float4 xv = px[c];
      const float xs[4] = {xv.x, xv.y, xv.z, xv.w};
      const int d0 = 4*c;
      #pragma unroll
      for (int u = 0; u < 4; ++u){
        const float xd = xs[u] * gbl[d0 + u];
        const float4* row = (const float4*)&wbl[(size_t)(d0+u)*EDIM];
        #pragma unroll
        for (int q8 = 0; q8 < 8; ++q8){
          float4 w = row[q8];
          acc[4*q8+0] = fmaf(xd, w.x, acc[4*q8+0]);
          acc[4*q8+1] = fmaf(xd, w.y, acc[4*q8+1]);
          acc[4*q8+2] = fmaf(xd, w.z, acc[4*q8+2]);
          acc[4*q8+3] = fmaf(xd, w.w, acc[4*q8+3]);
        }
      }
    }
    float* dst = P + ((size_t)l*NN + n)*64 + part*EDIM;
    #pragma unroll
    for (int q8 = 0; q8 < 8; ++q8)
      ((float4*)dst)[q8] = make_float4(acc[4*q8+0], acc[4*q8+1], acc[4*q8+2], acc[4*q8+3]);
  }
}

// =====================================================================
// Kernel B: edge update with precomputed node projections.
// Per edge per layer: S = P_A[i] + P_B[j] + (g_e .* e) @ W1_erows,
// LN stats from nstat + e-sums, then leaky + W2 + residual.
// Weights for ALL 3 layers staged in LDS once — no barriers in main loop.
// =====================================================================
__global__ __launch_bounds__(TPB, 2) void edge_mlp_pre(
  const float* __restrict__ ew, const float* __restrict__ lng,
  const float* __restrict__ w1, const float* __restrict__ w2,
  const float* __restrict__ b2,
  const int* __restrict__ ei, const int* __restrict__ ej,
  const float* __restrict__ P, const float* __restrict__ nstat,
  const float* __restrict__ cvec, float* __restrict__ out)
{
  __shared__ float sW1E[NLAYER*EDIM*EDIM];  // 12 KB: raw W1 rows 128..159
  __shared__ float sW2 [NLAYER*EDIM*EDIM];  // 12 KB
  __shared__ float sGE [NLAYER*EDIM];
  __shared__ float sC2 [NLAYER*EDIM], sC1b[NLAYER*EDIM], sB2v[NLAYER*EDIM];

  const int tid = threadIdx.x;
  #pragma unroll
  for (int it = 0; it < 3; ++it){          // W1E: 768 float4
    const int c = tid + it*TPB;
    const int l = c >> 8, rem = c & 255;
    const int d = rem >> 3, ks = (rem & 7) * 4;
    float4 v = *(const float4*)(w1 + (size_t)l*INDIM*EDIM + (size_t)(128+d)*EDIM + ks);
    float* dst = &sW1E[l*EDIM*EDIM + d*EDIM + ks];
    dst[0]=v.x; dst[1]=v.y; dst[2]=v.z; dst[3]=v.w;
  }
  #pragma unroll
  for (int it = 0; it < 3; ++it){          // W2: contiguous 3072 floats
    const int c = tid + it*TPB;
    float4 v = ((const float4*)w2)[c];
    float* dst = &sW2[4*c];
    dst[0]=v.x; dst[1]=v.y; dst[2]=v.z; dst[3]=v.w;
  }
  if (tid < 96){
    sGE [tid] = lng[(tid>>5)*INDIM + 128 + (tid&31)];
    sB2v[tid] = b2[tid];
    sC2 [tid] = cvec[tid];
    sC1b[tid] = cvec[96 + tid];
  }
  __syncthreads();

  const int id0 = blockIdx.x * EPB + tid;
  const int id1 = id0 + TPB;
  const int i0 = ei[id0], j0 = ej[id0];
  const int i1 = ei[id1], j1 = ej[id1];

  const float2 sti0 = *(const float2*)(nstat + 2*(size_t)i0);
  const float2 stj0 = *(const float2*)(nstat + 2*(size_t)j0);
  const float2 sti1 = *(const float2*)(nstat + 2*(size_t)i1);
  const float2 stj1 = *(const float2*)(nstat + 2*(size_t)j1);
  const float sn0 = sti0.x + stj0.x, qn0 = sti0.y + stj0.y;
  const float sn1 = sti1.x + stj1.x, qn1 = sti1.y + stj1.y;

  float e0[EDIM], e1[EDIM];
  {
    const float4* a = (const float4*)(ew + (size_t)id0 * EDIM);
    const float4* b = (const float4*)(ew + (size_t)id1 * EDIM);
    #pragma unroll
    for (int c = 0; c < 8; ++c){
      float4 v = a[c];
      e0[4*c+0]=v.x; e0[4*c+1]=v.y; e0[4*c+2]=v.z; e0[4*c+3]=v.w;
      float4 u = b[c];
      e1[4*c+0]=u.x; e1[4*c+1]=u.y; e1[4*c+2]=u.z; e1[4*c+3]=u.w;
    }
  }

  #pragma unroll 1
  for (int l = 0; l < NLAYER; ++l){
    const float* Pl = P + (size_t)l * NN * 64;
    const float4* a0v = (const float4*)(Pl + (size_t)i0*64);
    const float4* b0v = (const float4*)(Pl + (size_t)j0*64 + EDIM);
    const float4* a1v = (const float4*)(Pl + (size_t)i1*64);
    const float4* b1v = (const float4*)(Pl + (size_t)j1*64 + EDIM);

    // S init = gathered node projections (both endpoints)
    float S0[EDIM], S1[EDIM];
    #pragma unroll
    for (int c = 0; c < 8; ++c){
      float4 u = a0v[c], v = b0v[c];
      S0[4*c+0]=u.x+v.x; S0[4*c+1]=u.y+v.y; S0[4*c+2]=u.z+v.z; S0[4*c+3]=u.w+v.w;
      float4 p = a1v[c], r = b1v[c];
      S1[4*c+0]=p.x+r.x; S1[4*c+1]=p.y+r.y; S1[4*c+2]=p.z+r.z; S1[4*c+3]=p.w+r.w;
    }

    // LN stats: node partials + e-sums (independent of gathers — covers latency)
    float se0=0.f, qe0=0.f, se1=0.f, qe1=0.f;
    #pragma unroll
    for (int d = 0; d < EDIM; ++d){
      se0 += e0[d]; qe0 = fmaf(e0[d], e0[d], qe0);
      se1 += e1[d]; qe1 = fmaf(e1[d], e1[d], qe1);
    }
    const float mu0 = (sn0 + se0) * (1.f/INDIM);
    const float va0 = fmaxf(fmaf(-mu0, mu0, (qn0 + qe0) * (1.f/INDIM)), 0.f);
    const float rs0 = rsqrtf(va0 + 1e-5f);
    const float nm0 = -mu0 * rs0;
    const float mu1 = (sn1 + se1) * (1.f/INDIM);
    const float va1 = fmaxf(fmaf(-mu1, mu1, (qn1 + qe1) * (1.f/INDIM)), 0.f);
    const float rs1 = rsqrtf(va1 + 1e-5f);
    const float nm1 = -mu1 * rs1;

    // e-part of matmul1: S += (g_e .* e) @ W1_erows
    const float* wE = &sW1E[l*EDIM*EDIM];
    const float* gE = &sGE[l*EDIM];
    #pragma unroll
    for (int d = 0; d < EDIM; ++d){
      const float xd0 = gE[d]*e0[d], xd1 = gE[d]*e1[d];
      const float4* row = (const float4*)&wE[d*EDIM];
      #pragma unroll
      for (int q = 0; q < 8; ++q){
        float4 w = row[q];
        S0[4*q+0]=fmaf(xd0,w.x,S0[4*q+0]); S1[4*q+0]=fmaf(xd1,w.x,S1[4*q+0]);
        S0[4*q+1]=fmaf(xd0,w.y,S0[4*q+1]); S1[4*q+1]=fmaf(xd1,w.y,S1[4*q+1]);
        S0[4*q+2]=fmaf(xd0,w.z,S0[4*q+2]); S1[4*q+2]=fmaf(xd1,w.z,S1[4*q+2]);
        S0[4*q+3]=fmaf(xd0,w.w,S0[4*q+3]); S1[4*q+3]=fmaf(xd1,w.w,S1[4*q+3]);
      }
    }

    // LN epilogue + LeakyReLU (reuse S as h)
    const float* c2  = &sC2 [l*EDIM];
    const float* c1b = &sC1b[l*EDIM];
    const float* bb2 = &sB2v[l*EDIM];
    #pragma unroll
    for (int k = 0; k < EDIM; ++k){
      float a = fmaf(rs0, S0[k], fmaf(nm0, c2[k], c1b[k]));
      S0[k] = fmaxf(a, 0.01f*a);
      float b = fmaf(rs1, S1[k], fmaf(nm1, c2[k], c1b[k]));
      S1[k] = fmaxf(b, 0.01f*b);
    }
    #pragma unroll
    for (int k = 0; k < EDIM; ++k){ e0[k] += bb2[k]; e1[k] += bb2[k]; }

    // second linear, accumulate into e (residual)
    const float* w2l = &sW2[l*EDIM*EDIM];
    #pragma unroll
    for (int d = 0; d < EDIM; ++d){
      const float a = S0[d], b = S1[d];
      const float4* row = (const float4*)&w2l[d*EDIM];
      #pragma unroll
      for (int q = 0; q < 8; ++q){
        float4 w = row[q];
        e0[4*q+0]=fmaf(a,w.x,e0[4*q+0]); e1[4*q+0]=fmaf(b,w.x,e1[4*q+0]);
        e0[4*q+1]=fmaf(a,w.y,e0[4*q+1]); e1[4*q+1]=fmaf(b,w.y,e1[4*q+1]);
        e0[4*q+2]=fmaf(a,w.z,e0[4*q+2]); e1[4*q+2]=fmaf(b,w.z,e1[4*q+2]);
        e0[4*q+3]=fmaf(a,w.w,e0[4*q+3]); e1[4*q+3]=fmaf(b,w.w,e1[4*q+3]);
      }
    }
  }

  float4* o0 = (float4*)(out + (size_t)id0 * EDIM);
  float4* o1 = (float4*)(out + (size_t)id1 * EDIM);
  #pragma unroll
  for (int c = 0; c < 8; ++c){
    o0[c] = make_float4(e0[4*c+0], e0[4*c+1], e0[4*c+2], e0[4*c+3]);
    o1[c] = make_float4(e1[4*c+0], e1[4*c+1], e1[4*c+2], e1[4*c+3]);
  }
}

// =====================================================================
// Fallback: previous session's best kernel (1534 µs), used if workspace
// is too small for the projection tables.
// =====================================================================
__global__ __launch_bounds__(TPB, 2) void edge_mlp_fused(
  const float* __restrict__ nf,  const float* __restrict__ ew,
  const float* __restrict__ lng, const float* __restrict__ lnb,
  const float* __restrict__ w1,  const float* __restrict__ b1,
  const float* __restrict__ w2,  const float* __restrict__ b2,
  const int* __restrict__ ei, const int* __restrict__ ej,
  float* __restrict__ out)
{
  __shared__ float sW1[INDIM*EDIM];
  __shared__ float sW2[EDIM*EDIM];
  __shared__ float sC2[EDIM], sC1b[EDIM], sB2[EDIM];

  const int tid = threadIdx.x;
  const int id0 = blockIdx.x * EPB + tid;
  const int id1 = id0 + TPB;

  const float4* pi0 = (const float4*)(nf + (size_t)ei[id0] * NDIM);
  const float4* pj0 = (const float4*)(nf + (size_t)ej[id0] * NDIM);
  const float4* pi1 = (const float4*)(nf + (size_t)ei[id1] * NDIM);
  const float4* pj1 = (const float4*)(nf + (size_t)ej[id1] * NDIM);

  float e0[EDIM], e1[EDIM];
  {
    const float4* a = (const float4*)(ew + (size_t)id0 * EDIM);
    const float4* b = (const float4*)(ew + (size_t)id1 * EDIM);
    #pragma unroll
    for (int c = 0; c < 8; ++c){
      float4 v = a[c];
      e0[4*c+0]=v.x; e0[4*c+1]=v.y; e0[4*c+2]=v.z; e0[4*c+3]=v.w;
      float4 u = b[c];
      e1[4*c+0]=u.x; e1[4*c+1]=u.y; e1[4*c+2]=u.z; e1[4*c+3]=u.w;
    }
  }

  #pragma unroll 1
  for (int l = 0; l < NLAYER; ++l){
    __syncthreads();
    const float* w1l = w1 + (size_t)l * INDIM * EDIM;

    #pragma unroll
    for (int it = 0; it < 5; ++it){
      const int c = tid + it * TPB;
      const int d = c >> 3, ks = (c & 7) * 4;
      float4 v = *(const float4*)(w1l + d * EDIM + ks);
      const float g = lng[l * INDIM + d];
      sW1[d*EDIM+ks+0] = g*v.x; sW1[d*EDIM+ks+1] = g*v.y;
      sW1[d*EDIM+ks+2] = g*v.z; sW1[d*EDIM+ks+3] = g*v.w;
    }
    {
      const int d = tid >> 3, ks = (tid & 7) * 4;
      float4 v = *(const float4*)(w2 + (size_t)l*EDIM*EDIM + d*EDIM + ks);
      sW2[d*EDIM+ks+0] = v.x; sW2[d*EDIM+ks+1] = v.y;
      sW2[d*EDIM+ks+2] = v.z; sW2[d*EDIM+ks+3] = v.w;
    }
    if (tid < EDIM){
      float c1 = b1[l*EDIM + tid];
      for (int d = 0; d < INDIM; ++d)
        c1 = fmaf(lnb[l*INDIM + d], w1l[d*EDIM + tid], c1);
      sC1b[tid] = c1;
      sB2[tid]  = b2[l*EDIM + tid];
    }
    __syncthreads();
    if (tid < EDIM){
      float s = 0.f;
      for (int d = 0; d < INDIM; ++d) s += sW1[d*EDIM + tid];
      sC2[tid] = s;
    }
    __syncthreads();

    float S0[EDIM], S1[EDIM];
    #pragma unroll
    for (int k = 0; k < EDIM; ++k){ S0[k] = 0.f; S1[k] = 0.f; }
    float sum0 = 0.f, sq0 = 0.f, sum1 = 0.f, sq1 = 0.f;

    auto dot_row = [&](float xv0, float xv1, const float4* row){
      sum0 += xv0; sq0 = fmaf(xv0, xv0, sq0);
      sum1 += xv1; sq1 = fmaf(xv1, xv1, sq1);
      #pragma unroll
      for (int q = 0; q < 8; ++q){
        float4 w = row[q];
        S0[4*q+0] = fmaf(xv0, w.x, S0[4*q+0]); S1[4*q+0] = fmaf(xv1, w.x, S1[4*q+0]);
        S0[4*q+1] = fmaf(xv0, w.y, S0[4*q+1]); S1[4*q+1] = fmaf(xv1, w.y, S1[4*q+1]);
        S0[4*q+2] = fmaf(xv0, w.z, S0[4*q+2]); S1[4*q+2] = fmaf(xv1, w.z, S1[4*q+2]);
        S0[4*q+3] = fmaf(xv0, w.w, S0[4*q+3]); S1[4*q+3] = fmaf(xv1, w.w, S1[4*q+3]);
      }
    };

    #pragma unroll 1
    for (int c = 0; c < 32; ++c){
      const float4 x0 = (c < 16) ? pi0[c] : pj0[c - 16];
      const float4 x1 = (c < 16) ? pi1[c] : pj1[c - 16];
      const float4* wr = (const float4*)&sW1[c * 4 * EDIM];
      dot_row(x0.x, x1.x, wr + 0);
      dot_row(x0.y, x1.y, wr + 8);
      dot_row(x0.z, x1.z, wr + 16);
      dot_row(x0.w, x1.w, wr + 24);
    }
    #pragma unroll
    for (int d = 0; d < EDIM; ++d){
      const float4* row = (const float4*)&sW1[(2*NDIM + d) * EDIM];
      dot_row(e0[d], e1[d], row);
    }

    const float mu0 = sum0 * (1.f/INDIM);
    const float va0 = fmaxf(fmaf(-mu0, mu0, sq0 * (1.f/INDIM)), 0.f);
    const float rs0 = rsqrtf(va0 + 1e-5f);
    const float nm0 = -mu0 * rs0;
    const float mu1 = sum1 * (1.f/INDIM);
    const float va1 = fmaxf(fmaf(-mu1, mu1, sq1 * (1.f/INDIM)), 0.f);
    const float rs1 = rsqrtf(va1 + 1e-5f);
    const float nm1 = -mu1 * rs1;

    float h0[EDIM], h1v[EDIM];
    #pragma unroll
    for (int k = 0; k < EDIM; ++k){
      float a = fmaf(rs0, S0[k], fmaf(nm0, sC2[k], sC1b[k]));
      h0[k]  = fmaxf(a, 0.01f * a);
      float b = fmaf(rs1, S1[k], fmaf(nm1, sC2[k], sC1b[k]));
      h1v[k] = fmaxf(b, 0.01f * b);
    }
    #pragma unroll
    for (int k = 0; k < EDIM; ++k){ e0[k] += sB2[k]; e1[k] += sB2[k]; }
    #pragma unroll
    for (int d = 0; d < EDIM; ++d){
      const float a = h0[d], b = h1v[d];
      const float4* row = (const float4*)&sW2[d * EDIM];
      #pragma unroll
      for (int q = 0; q < 8; ++q){
        float4 w = row[q];
        e0[4*q+0] = fmaf(a, w.x, e0[4*q+0]); e1[4*q+0] = fmaf(b, w.x, e1[4*q+0]);
        e0[4*q+1] = fmaf(a, w.y, e0[4*q+1]); e1[4*q+1] = fmaf(b, w.y, e1[4*q+1]);
        e0[4*q+2] = fmaf(a, w.z, e0[4*q+2]); e1[4*q+2] = fmaf(b, w.z, e1[4*q+2]);
        e0[4*q+3] = fmaf(a, w.w, e0[4*q+3]); e1[4*q+3] = fmaf(b, w.w, e1[4*q+3]);
      }
    }
  }

  float4* o0 = (float4*)(out + (size_t)id0 * EDIM);
  float4* o1 = (float4*)(out + (size_t)id1 * EDIM);
  #pragma unroll
  for (int c = 0; c < 8; ++c){
    o0[c] = make_float4(e0[4*c+0], e0[4*c+1], e0[4*c+2], e0[4*c+3]);
    o1[c] = make_float4(e1[4*c+0], e1[4*c+1], e1[4*c+2], e1[4*c+3]);
  }
}

extern "C" void kernel_launch(void* const* d_in, const int* in_sizes, int n_in,
                              void* d_out, int out_size, void* d_ws, size_t ws_size,
                              hipStream_t stream)
{
  const float* nf  = (const float*)d_in[0];
  const float* ew  = (const float*)d_in[1];
  const float* lng = (const float*)d_in[2];
  const float* lnb = (const float*)d_in[3];
  const float* w1  = (const float*)d_in[4];
  const float* b1  = (const float*)d_in[5];
  const float* w2  = (const float*)d_in[6];
  const float* b2  = (const float*)d_in[7];
  const int*   ei  = (const int*)d_in[8];
  const int*   ej  = (const int*)d_in[9];
  float* out = (float*)d_out;

  const size_t PBYTES = (size_t)NLAYER * NN * 64 * sizeof(float);  // 76.8 MB
  const size_t SBYTES = (size_t)NN * 2 * sizeof(float);            // 800 KB
  const size_t CBYTES = (size_t)2 * NLAYER * EDIM * sizeof(float); // 768 B

  if (d_ws && ws_size >= PBYTES + SBYTES + CBYTES){
    float* P     = (float*)d_ws;
    float* nstat = (float*)((char*)d_ws + PBYTES);
    float* cvec  = (float*)((char*)d_ws + PBYTES + SBYTES);
    hipLaunchKernelGGL(node_precompute, dim3((NN + TPB - 1)/TPB), dim3(TPB), 0, stream,
                       nf, lng, lnb, w1, b1, P, nstat, cvec);
    hipLaunchKernelGGL(edge_mlp_pre, dim3(EE / EPB), dim3(TPB), 0, stream,
                       ew, lng, w1, w2, b2, ei, ej, P, nstat, cvec, out);
  } else {
    dim3 grid(EE / EPB), block(TPB);
    hipLaunchKernelGGL(edge_mlp_fused, grid, block, 0, stream,
                       nf, ew, lng, lnb, w1, b1, w2, b2, ei, ej, out);
  }
}

// Round 2
// 898.927 us; speedup vs baseline: 1.2384x; 1.2384x over previous
//
#include <hip/hip_runtime.h>

#define EE     1600000
#define NN     100000
#define NDIM   64
#define EDIM   32
#define NLAYER 3
#define INDIM  160      // EDIM + 2*NDIM
#define TPB    256

static_assert(EE % TPB == 0, "grid must divide evenly");

// =====================================================================
// Kernel A: per-node projection precompute, split 6-way over (layer,part)
// for parallelism (2346 blocks vs 391).
//   P[l][n][0:32]  = sum_{d<64} nf[n][d] * g_l[d]    * W1_l[d][k]
//   P[l][n][32:64] = sum_{d<64} nf[n][d] * g_l[64+d] * W1_l[64+d][k]
//   nstat[n] = (sum nf, sum nf^2); cvec = folded LN constants.
// =====================================================================
__global__ __launch_bounds__(TPB) void node_precompute(
  const float* __restrict__ nf,  const float* __restrict__ lng,
  const float* __restrict__ lnb, const float* __restrict__ w1,
  const float* __restrict__ b1,
  float* __restrict__ P, float* __restrict__ nstat, float* __restrict__ cvec)
{
  __shared__ float sW[64*EDIM];   // 8 KB: this (l,part)'s 64 W1 rows
  __shared__ float sG[64];
  const int tid  = threadIdx.x;
  const int lp   = blockIdx.y;          // 0..5
  const int l    = lp >> 1, part = lp & 1;

  // stage 64 rows x 32 cols = 512 float4, 2 per thread
  #pragma unroll
  for (int it = 0; it < 2; ++it){
    const int c = tid + it*TPB;
    const int d = c >> 3, ks = (c & 7) * 4;
    float4 v = *(const float4*)(w1 + (size_t)l*INDIM*EDIM + (size_t)(part*64 + d)*EDIM + ks);
    float* dst = &sW[d*EDIM + ks];
    dst[0]=v.x; dst[1]=v.y; dst[2]=v.z; dst[3]=v.w;
  }
  if (tid < 16){
    float4 v = *(const float4*)(lng + l*INDIM + part*64 + tid*4);
    sG[4*tid+0]=v.x; sG[4*tid+1]=v.y; sG[4*tid+2]=v.z; sG[4*tid+3]=v.w;
  }
  __syncthreads();

  // folded LN constants (one block only)
  if (lp == 0 && blockIdx.x == 0 && tid < 96){
    const int ll = tid >> 5, k = tid & 31;
    const float* wl = w1 + (size_t)ll*INDIM*EDIM;
    float c2 = 0.f, c1 = b1[ll*EDIM + k];
    for (int d = 0; d < INDIM; ++d){
      const float w = wl[d*EDIM + k];
      c2 = fmaf(lng[ll*INDIM + d], w, c2);
      c1 = fmaf(lnb[ll*INDIM + d], w, c1);
    }
    cvec[ll*EDIM + k]      = c2;
    cvec[96 + ll*EDIM + k] = c1;
  }

  const int n = blockIdx.x*TPB + tid;
  if (n >= NN) return;
  const float4* px = (const float4*)(nf + (size_t)n * NDIM);

  if (lp == 0){   // layer-invariant LN partial sums, written once
    float s = 0.f, q = 0.f;
    #pragma unroll 1
    for (int c = 0; c < 16; ++c){
      float4 v = px[c];
      s += v.x + v.y + v.z + v.w;
      q = fmaf(v.x,v.x,q); q = fmaf(v.y,v.y,q);
      q = fmaf(v.z,v.z,q); q = fmaf(v.w,v.w,q);
    }
    nstat[2*n] = s; nstat[2*n+1] = q;
  }

  float acc[EDIM];
  #pragma unroll
  for (int k = 0; k < EDIM; ++k) acc[k] = 0.f;
  #pragma unroll 1
  for (int c = 0; c < 16; ++c){
    float4 xv = px[c];
    const float xs[4] = {xv.x, xv.y, xv.z, xv.w};
    const int d0 = 4*c;
    #pragma unroll
    for (int u = 0; u < 4; ++u){
      const float xd = xs[u] * sG[d0 + u];
      const float4* row = (const float4*)&sW[(size_t)(d0+u)*EDIM];
      #pragma unroll
      for (int q8 = 0; q8 < 8; ++q8){
        float4 w = row[q8];
        acc[4*q8+0] = fmaf(xd, w.x, acc[4*q8+0]);
        acc[4*q8+1] = fmaf(xd, w.y, acc[4*q8+1]);
        acc[4*q8+2] = fmaf(xd, w.z, acc[4*q8+2]);
        acc[4*q8+3] = fmaf(xd, w.w, acc[4*q8+3]);
      }
    }
  }
  float* dst = P + ((size_t)l*NN + n)*64 + part*EDIM;
  #pragma unroll
  for (int q8 = 0; q8 < 8; ++q8)
    ((float4*)dst)[q8] = make_float4(acc[4*q8+0], acc[4*q8+1], acc[4*q8+2], acc[4*q8+3]);
}

// =====================================================================
// Kernel B: edge update, ONE edge per thread (EPT=1).
// e[32]+S[32] = 64 floats of array state -> spill-free under 128 VGPR,
// 4 blocks/CU occupancy for gather latency hiding.
// =====================================================================
__global__ __launch_bounds__(TPB, 4) void edge_mlp_pre(
  const float* __restrict__ ew, const float* __restrict__ lng,
  const float* __restrict__ w1, const float* __restrict__ w2,
  const float* __restrict__ b2,
  const int* __restrict__ ei, const int* __restrict__ ej,
  const float* __restrict__ P, const float* __restrict__ nstat,
  const float* __restrict__ cvec, float* __restrict__ out)
{
  __shared__ float sW1E[NLAYER*EDIM*EDIM];  // 12 KB: raw W1 rows 128..159
  __shared__ float sW2 [NLAYER*EDIM*EDIM];  // 12 KB
  __shared__ float sGE [NLAYER*EDIM];
  __shared__ float sC2 [NLAYER*EDIM], sC1b[NLAYER*EDIM], sB2v[NLAYER*EDIM];

  const int tid = threadIdx.x;
  #pragma unroll
  for (int it = 0; it < 3; ++it){          // W1E: 768 float4
    const int c = tid + it*TPB;
    const int l = c >> 8, rem = c & 255;
    const int d = rem >> 3, ks = (rem & 7) * 4;
    float4 v = *(const float4*)(w1 + (size_t)l*INDIM*EDIM + (size_t)(128+d)*EDIM + ks);
    float* dst = &sW1E[l*EDIM*EDIM + d*EDIM + ks];
    dst[0]=v.x; dst[1]=v.y; dst[2]=v.z; dst[3]=v.w;
  }
  #pragma unroll
  for (int it = 0; it < 3; ++it){          // W2: contiguous 3072 floats
    const int c = tid + it*TPB;
    float4 v = ((const float4*)w2)[c];
    float* dst = &sW2[4*c];
    dst[0]=v.x; dst[1]=v.y; dst[2]=v.z; dst[3]=v.w;
  }
  if (tid < 96){
    sGE [tid] = lng[(tid>>5)*INDIM + 128 + (tid&31)];
    sB2v[tid] = b2[tid];
    sC2 [tid] = cvec[tid];
    sC1b[tid] = cvec[96 + tid];
  }
  __syncthreads();

  const int id = blockIdx.x * TPB + tid;
  const int i = ei[id], j = ej[id];

  const float2 sti = *(const float2*)(nstat + 2*(size_t)i);
  const float2 stj = *(const float2*)(nstat + 2*(size_t)j);
  const float sn = sti.x + stj.x, qn = sti.y + stj.y;

  float e[EDIM];
  {
    const float4* a = (const float4*)(ew + (size_t)id * EDIM);
    #pragma unroll
    for (int c = 0; c < 8; ++c){
      float4 v = a[c];
      e[4*c+0]=v.x; e[4*c+1]=v.y; e[4*c+2]=v.z; e[4*c+3]=v.w;
    }
  }

  #pragma unroll 1
  for (int l = 0; l < NLAYER; ++l){
    const float* Pl = P + (size_t)l * NN * 64;
    const float4* av = (const float4*)(Pl + (size_t)i*64);
    const float4* bv = (const float4*)(Pl + (size_t)j*64 + EDIM);

    // S init = gathered node projections (i-part + j-part)
    float S[EDIM];
    #pragma unroll
    for (int c = 0; c < 8; ++c){
      float4 u = av[c], v = bv[c];
      S[4*c+0]=u.x+v.x; S[4*c+1]=u.y+v.y; S[4*c+2]=u.z+v.z; S[4*c+3]=u.w+v.w;
    }

    // LN stats: node partials + e-sums
    float se = 0.f, qe = 0.f;
    #pragma unroll
    for (int d = 0; d < EDIM; ++d){
      se += e[d]; qe = fmaf(e[d], e[d], qe);
    }
    const float mu = (sn + se) * (1.f/INDIM);
    const float va = fmaxf(fmaf(-mu, mu, (qn + qe) * (1.f/INDIM)), 0.f);
    const float rs = rsqrtf(va + 1e-5f);
    const float nm = -mu * rs;

    // e-part of matmul1: S += (g_e .* e) @ W1_erows
    const float* wE = &sW1E[l*EDIM*EDIM];
    const float* gE = &sGE[l*EDIM];
    #pragma unroll
    for (int d = 0; d < EDIM; ++d){
      const float xd = gE[d]*e[d];
      const float4* row = (const float4*)&wE[d*EDIM];
      #pragma unroll
      for (int q = 0; q < 8; ++q){
        float4 w = row[q];
        S[4*q+0]=fmaf(xd,w.x,S[4*q+0]);
        S[4*q+1]=fmaf(xd,w.y,S[4*q+1]);
        S[4*q+2]=fmaf(xd,w.z,S[4*q+2]);
        S[4*q+3]=fmaf(xd,w.w,S[4*q+3]);
      }
    }

    // LN epilogue + LeakyReLU (reuse S as h)
    const float* c2  = &sC2 [l*EDIM];
    const float* c1b = &sC1b[l*EDIM];
    const float* bb2 = &sB2v[l*EDIM];
    #pragma unroll
    for (int k = 0; k < EDIM; ++k){
      float a = fmaf(rs, S[k], fmaf(nm, c2[k], c1b[k]));
      S[k] = fmaxf(a, 0.01f*a);
    }
    #pragma unroll
    for (int k = 0; k < EDIM; ++k) e[k] += bb2[k];

    // second linear, accumulate into e (residual)
    const float* w2l = &sW2[l*EDIM*EDIM];
    #pragma unroll
    for (int d = 0; d < EDIM; ++d){
      const float a = S[d];
      const float4* row = (const float4*)&w2l[d*EDIM];
      #pragma unroll
      for (int q = 0; q < 8; ++q){
        float4 w = row[q];
        e[4*q+0]=fmaf(a,w.x,e[4*q+0]);
        e[4*q+1]=fmaf(a,w.y,e[4*q+1]);
        e[4*q+2]=fmaf(a,w.z,e[4*q+2]);
        e[4*q+3]=fmaf(a,w.w,e[4*q+3]);
      }
    }
  }

  float4* o = (float4*)(out + (size_t)id * EDIM);
  #pragma unroll
  for (int c = 0; c < 8; ++c)
    o[c] = make_float4(e[4*c+0], e[4*c+1], e[4*c+2], e[4*c+3]);
}

// =====================================================================
// Fallback: previous session's best fused kernel (1534 µs), used only if
// the workspace is too small for the projection tables.
// =====================================================================
#define EPT    2
#define EPB    (TPB*EPT)
static_assert(EE % EPB == 0, "grid must divide evenly");

__global__ __launch_bounds__(TPB, 2) void edge_mlp_fused(
  const float* __restrict__ nf,  const float* __restrict__ ew,
  const float* __restrict__ lng, const float* __restrict__ lnb,
  const float* __restrict__ w1,  const float* __restrict__ b1,
  const float* __restrict__ w2,  const float* __restrict__ b2,
  const int* __restrict__ ei, const int* __restrict__ ej,
  float* __restrict__ out)
{
  __shared__ float sW1[INDIM*EDIM];
  __shared__ float sW2[EDIM*EDIM];
  __shared__ float sC2[EDIM], sC1b[EDIM], sB2[EDIM];

  const int tid = threadIdx.x;
  const int id0 = blockIdx.x * EPB + tid;
  const int id1 = id0 + TPB;

  const float4* pi0 = (const float4*)(nf + (size_t)ei[id0] * NDIM);
  const float4* pj0 = (const float4*)(nf + (size_t)ej[id0] * NDIM);
  const float4* pi1 = (const float4*)(nf + (size_t)ei[id1] * NDIM);
  const float4* pj1 = (const float4*)(nf + (size_t)ej[id1] * NDIM);

  float e0[EDIM], e1[EDIM];
  {
    const float4* a = (const float4*)(ew + (size_t)id0 * EDIM);
    const float4* b = (const float4*)(ew + (size_t)id1 * EDIM);
    #pragma unroll
    for (int c = 0; c < 8; ++c){
      float4 v = a[c];
      e0[4*c+0]=v.x; e0[4*c+1]=v.y; e0[4*c+2]=v.z; e0[4*c+3]=v.w;
      float4 u = b[c];
      e1[4*c+0]=u.x; e1[4*c+1]=u.y; e1[4*c+2]=u.z; e1[4*c+3]=u.w;
    }
  }

  #pragma unroll 1
  for (int l = 0; l < NLAYER; ++l){
    __syncthreads();
    const float* w1l = w1 + (size_t)l * INDIM * EDIM;

    #pragma unroll
    for (int it = 0; it < 5; ++it){
      const int c = tid + it * TPB;
      const int d = c >> 3, ks = (c & 7) * 4;
      float4 v = *(const float4*)(w1l + d * EDIM + ks);
      const float g = lng[l * INDIM + d];
      sW1[d*EDIM+ks+0] = g*v.x; sW1[d*EDIM+ks+1] = g*v.y;
      sW1[d*EDIM+ks+2] = g*v.z; sW1[d*EDIM+ks+3] = g*v.w;
    }
    {
      const int d = tid >> 3, ks = (tid & 7) * 4;
      float4 v = *(const float4*)(w2 + (size_t)l*EDIM*EDIM + d*EDIM + ks);
      sW2[d*EDIM+ks+0] = v.x; sW2[d*EDIM+ks+1] = v.y;
      sW2[d*EDIM+ks+2] = v.z; sW2[d*EDIM+ks+3] = v.w;
    }
    if (tid < EDIM){
      float c1 = b1[l*EDIM + tid];
      for (int d = 0; d < INDIM; ++d)
        c1 = fmaf(lnb[l*INDIM + d], w1l[d*EDIM + tid], c1);
      sC1b[tid] = c1;
      sB2[tid]  = b2[l*EDIM + tid];
    }
    __syncthreads();
    if (tid < EDIM){
      float s = 0.f;
      for (int d = 0; d < INDIM; ++d) s += sW1[d*EDIM + tid];
      sC2[tid] = s;
    }
    __syncthreads();

    float S0[EDIM], S1[EDIM];
    #pragma unroll
    for (int k = 0; k < EDIM; ++k){ S0[k] = 0.f; S1[k] = 0.f; }
    float sum0 = 0.f, sq0 = 0.f, sum1 = 0.f, sq1 = 0.f;

    auto dot_row = [&](float xv0, float xv1, const float4* row){
      sum0 += xv0; sq0 = fmaf(xv0, xv0, sq0);
      sum1 += xv1; sq1 = fmaf(xv1, xv1, sq1);
      #pragma unroll
      for (int q = 0; q < 8; ++q){
        float4 w = row[q];
        S0[4*q+0] = fmaf(xv0, w.x, S0[4*q+0]); S1[4*q+0] = fmaf(xv1, w.x, S1[4*q+0]);
        S0[4*q+1] = fmaf(xv0, w.y, S0[4*q+1]); S1[4*q+1] = fmaf(xv1, w.y, S1[4*q+1]);
        S0[4*q+2] = fmaf(xv0, w.z, S0[4*q+2]); S1[4*q+2] = fmaf(xv1, w.z, S1[4*q+2]);
        S0[4*q+3] = fmaf(xv0, w.w, S0[4*q+3]); S1[4*q+3] = fmaf(xv1, w.w, S1[4*q+3]);
      }
    };

    #pragma unroll 1
    for (int c = 0; c < 32; ++c){
      const float4 x0 = (c < 16) ? pi0[c] : pj0[c - 16];
      const float4 x1 = (c < 16) ? pi1[c] : pj1[c - 16];
      const float4* wr = (const float4*)&sW1[c * 4 * EDIM];
      dot_row(x0.x, x1.x, wr + 0);
      dot_row(x0.y, x1.y, wr + 8);
      dot_row(x0.z, x1.z, wr + 16);
      dot_row(x0.w, x1.w, wr + 24);
    }
    #pragma unroll
    for (int d = 0; d < EDIM; ++d){
      const float4* row = (const float4*)&sW1[(2*NDIM + d) * EDIM];
      dot_row(e0[d], e1[d], row);
    }

    const float mu0 = sum0 * (1.f/INDIM);
    const float va0 = fmaxf(fmaf(-mu0, mu0, sq0 * (1.f/INDIM)), 0.f);
    const float rs0 = rsqrtf(va0 + 1e-5f);
    const float nm0 = -mu0 * rs0;
    const float mu1 = sum1 * (1.f/INDIM);
    const float va1 = fmaxf(fmaf(-mu1, mu1, sq1 * (1.f/INDIM)), 0.f);
    const float rs1 = rsqrtf(va1 + 1e-5f);
    const float nm1 = -mu1 * rs1;

    float h0[EDIM], h1v[EDIM];
    #pragma unroll
    for (int k = 0; k < EDIM; ++k){
      float a = fmaf(rs0, S0[k], fmaf(nm0, sC2[k], sC1b[k]));
      h0[k]  = fmaxf(a, 0.01f * a);
      float b = fmaf(rs1, S1[k], fmaf(nm1, sC2[k], sC1b[k]));
      h1v[k] = fmaxf(b, 0.01f * b);
    }
    #pragma unroll
    for (int k = 0; k < EDIM; ++k){ e0[k] += sB2[k]; e1[k] += sB2[k]; }
    #pragma unroll
    for (int d = 0; d < EDIM; ++d){
      const float a = h0[d], b = h1v[d];
      const float4* row = (const float4*)&sW2[d * EDIM];
      #pragma unroll
      for (int q = 0; q < 8; ++q){
        float4 w = row[q];
        e0[4*q+0] = fmaf(a, w.x, e0[4*q+0]); e1[4*q+0] = fmaf(b, w.x, e1[4*q+0]);
        e0[4*q+1] = fmaf(a, w.y, e0[4*q+1]); e1[4*q+1] = fmaf(b, w.y, e1[4*q+1]);
        e0[4*q+2] = fmaf(a, w.z, e0[4*q+2]); e1[4*q+2] = fmaf(b, w.z, e1[4*q+2]);
        e0[4*q+3] = fmaf(a, w.w, e0[4*q+3]); e1[4*q+3] = fmaf(b, w.w, e1[4*q+3]);
      }
    }
  }

  float4* o0 = (float4*)(out + (size_t)id0 * EDIM);
  float4* o1 = (float4*)(out + (size_t)id1 * EDIM);
  #pragma unroll
  for (int c = 0; c < 8; ++c){
    o0[c] = make_float4(e0[4*c+0], e0[4*c+1], e0[4*c+2], e0[4*c+3]);
    o1[c] = make_float4(e1[4*c+0], e1[4*c+1], e1[4*c+2], e1[4*c+3]);
  }
}

extern "C" void kernel_launch(void* const* d_in, const int* in_sizes, int n_in,
                              void* d_out, int out_size, void* d_ws, size_t ws_size,
                              hipStream_t stream)
{
  const float* nf  = (const float*)d_in[0];
  const float* ew  = (const float*)d_in[1];
  const float* lng = (const float*)d_in[2];
  const float* lnb = (const float*)d_in[3];
  const float* w1  = (const float*)d_in[4];
  const float* b1  = (const float*)d_in[5];
  const float* w2  = (const float*)d_in[6];
  const float* b2  = (const float*)d_in[7];
  const int*   ei  = (const int*)d_in[8];
  const int*   ej  = (const int*)d_in[9];
  float* out = (float*)d_out;

  const size_t PBYTES = (size_t)NLAYER * NN * 64 * sizeof(float);  // 76.8 MB
  const size_t SBYTES = (size_t)NN * 2 * sizeof(float);            // 800 KB
  const size_t CBYTES = (size_t)2 * NLAYER * EDIM * sizeof(float); // 768 B

  if (d_ws && ws_size >= PBYTES + SBYTES + CBYTES){
    float* P     = (float*)d_ws;
    float* nstat = (float*)((char*)d_ws + PBYTES);
    float* cvec  = (float*)((char*)d_ws + PBYTES + SBYTES);
    hipLaunchKernelGGL(node_precompute,
                       dim3((NN + TPB - 1)/TPB, 6), dim3(TPB), 0, stream,
                       nf, lng, lnb, w1, b1, P, nstat, cvec);
    hipLaunchKernelGGL(edge_mlp_pre, dim3(EE / TPB), dim3(TPB), 0, stream,
                       ew, lng, w1, w2, b2, ei, ej, P, nstat, cvec, out);
  } else {
    dim3 grid(EE / EPB), block(TPB);
    hipLaunchKernelGGL(edge_mlp_fused, grid, block, 0, stream,
                       nf, ew, lng, lnb, w1, b1, w2, b2, ei, ej, out);
  }
}